// Round 3
// baseline (159.838 us; speedup 1.0000x reference)
//
#include <hip/hip_runtime.h>
#include <math.h>

// Problem constants
#define NB   16
#define HW   65536          // 256*256
#define NCHM 32             // minmax pixel-chunks per batch
#define NCHH 16             // hist pixel-chunks per (b,pair)

// Workspace layout (float offsets)
#define OFF_S    0          // [16][65536] channel-summed 3x3 box / 9 (dead after k_hist_part)
#define OFF_D    0          // [16][9][64][56] per-cell tap dot-products (overwrites dead S)
#define OFF_PH   1048576    // [1024][64] partial hists
#define OFF_PMN  1114112    // [128][32] partial mins
#define OFF_PMX  1118208    // [128][32] partial maxs
// total floats: 1122304 (~4.49 MB)

__device__ __forceinline__ float leakyf(float v) { return v >= 0.f ? v : 0.01f * v; }

// K1: S[b][h][w] = (sum over 3x3 zero-padded neighborhood of (x0+x1+x2)) / 9
__global__ void k_box(const float* __restrict__ x, float* __restrict__ ws)
{
    __shared__ float t[18][20];
    int b  = blockIdx.z;
    int h0 = blockIdx.y * 16, w0 = blockIdx.x * 16;
    int tid = threadIdx.y * 16 + threadIdx.x;
    const float* xb = x + (size_t)b * 3 * HW;
    for (int i = tid; i < 18 * 18; i += 256) {
        int lh = i / 18, lw = i % 18;
        int gh = h0 - 1 + lh, gw = w0 - 1 + lw;
        float v = 0.f;
        if (gh >= 0 && gh < 256 && gw >= 0 && gw < 256) {
            int p = gh * 256 + gw;
            v = xb[p] + xb[HW + p] + xb[2 * HW + p];
        }
        t[lh][lw] = v;
    }
    __syncthreads();
    int ty = threadIdx.y, tx = threadIdx.x;
    float s = 0.f;
    #pragma unroll
    for (int dy = 0; dy < 3; ++dy)
        #pragma unroll
        for (int dx = 0; dx < 3; ++dx)
            s += t[ty + dy][tx + dx];
    ws[OFF_S + b * HW + (h0 + ty) * 256 + (w0 + tx)] = s / 9.0f;
}

// K2: per (b, chunk) partial min/max for all 8 lbp directions at once.
__global__ void k_minmax_part(const float* __restrict__ clo, const float* __restrict__ chi,
                              float* ws)
{
    const int doy[8] = {-1, 1, -1, 1, -1, 1, 0, 0};
    const int dox[8] = {-1, 1,  0, 0,  1, -1, 1, -1};
    int b  = blockIdx.x / NCHM;
    int ch = blockIdx.x % NCHM;
    float lo = clo[0], hi = chi[0];
    const float* Sb = ws + OFF_S + b * HW;
    float vmn[8], vmx[8];
    #pragma unroll
    for (int o = 0; o < 8; ++o) { vmn[o] = 3.4e38f; vmx[o] = -3.4e38f; }
    int base = ch * (HW / NCHM);
    #pragma unroll
    for (int it = 0; it < (HW / NCHM) / 256; ++it) {
        int p = base + it * 256 + threadIdx.x;
        int h = p >> 8, w = p & 255;
        float sc = Sb[p];
        #pragma unroll
        for (int o = 0; o < 8; ++o) {
            int nh = h + doy[o], nw = w + dox[o];
            float off = ((unsigned)nh < 256u && (unsigned)nw < 256u) ? Sb[nh * 256 + nw] : 0.f;
            float v = fminf(fmaxf(sc - off, lo), hi);
            vmn[o] = fminf(vmn[o], v);
            vmx[o] = fmaxf(vmx[o], v);
        }
    }
    #pragma unroll
    for (int o = 0; o < 8; ++o) {
        #pragma unroll
        for (int m = 1; m < 64; m <<= 1) {
            vmn[o] = fminf(vmn[o], __shfl_xor(vmn[o], m));
            vmx[o] = fmaxf(vmx[o], __shfl_xor(vmx[o], m));
        }
    }
    __shared__ float smn[4][8], smx[4][8];
    int wid = threadIdx.x >> 6, lane = threadIdx.x & 63;
    if (lane == 0) {
        #pragma unroll
        for (int o = 0; o < 8; ++o) { smn[wid][o] = vmn[o]; smx[wid][o] = vmx[o]; }
    }
    __syncthreads();
    if (threadIdx.x < 8) {
        int o = threadIdx.x;
        float mn = fminf(fminf(smn[0][o], smn[1][o]), fminf(smn[2][o], smn[3][o]));
        float mx = fmaxf(fmaxf(smx[0][o], smx[1][o]), fmaxf(smx[2][o], smx[3][o]));
        ws[OFF_PMN + (b * 8 + o) * NCHM + ch] = mn;
        ws[OFF_PMX + (b * 8 + o) * NCHM + ch] = mx;
    }
}

// K3: partial joint 8x8 histogram per (b, pair g, chunk). Reduces min/max partials inline.
__global__ void k_hist_part(const float* __restrict__ clo, const float* __restrict__ chi,
                            float* ws)
{
    __shared__ float lh[64 * 64];   // [bin][col]
    const int doy[8] = {-1, 1, -1, 1, -1, 1, 0, 0};
    const int dox[8] = {-1, 1,  0, 0,  1, -1, 1, -1};
    int bg = blockIdx.x / NCHH;
    int ch = blockIdx.x % NCHH;
    int b = bg >> 2, g = bg & 3;
    int dy0 = doy[2 * g], dx0 = dox[2 * g];
    int dy1 = doy[2 * g + 1], dx1 = dox[2 * g + 1];
    // inline reduce of min/max partials (order-independent, exact)
    float mn0 = 3.4e38f, mx0 = -3.4e38f, mn1 = 3.4e38f, mx1 = -3.4e38f;
    {
        int c0 = (b * 8 + 2 * g) * NCHM, c1 = (b * 8 + 2 * g + 1) * NCHM;
        for (int c = 0; c < NCHM; ++c) {
            mn0 = fminf(mn0, ws[OFF_PMN + c0 + c]);
            mx0 = fmaxf(mx0, ws[OFF_PMX + c0 + c]);
            mn1 = fminf(mn1, ws[OFF_PMN + c1 + c]);
            mx1 = fmaxf(mx1, ws[OFF_PMX + c1 + c]);
        }
    }
    float r0 = mx0 - mn0, r1 = mx1 - mn1;
    float lev0[8], lev1[8];
    #pragma unroll
    for (int q = 0; q < 8; ++q) {
        lev0[q] = __fadd_rn(mn0, __fmul_rn(r0, (float)q * 0.125f));
        lev1[q] = __fadd_rn(mn1, __fmul_rn(r1, (float)q * 0.125f));
    }
    const float* Sb = ws + OFF_S + b * HW;
    for (int i = threadIdx.x; i < 4096; i += 256) lh[i] = 0.f;
    __syncthreads();
    int col = threadIdx.x & 63;
    float lo = clo[0], hi = chi[0];
    int base = ch * (HW / NCHH);
    #pragma unroll
    for (int it = 0; it < (HW / NCHH) / 256; ++it) {
        int p = base + it * 256 + threadIdx.x;
        int h = p >> 8, w = p & 255;
        float off0 = 0.f, off1 = 0.f;
        int nh = h + dy0, nw = w + dx0;
        if ((unsigned)nh < 256u && (unsigned)nw < 256u) off0 = Sb[nh * 256 + nw];
        nh = h + dy1; nw = w + dx1;
        if ((unsigned)nh < 256u && (unsigned)nw < 256u) off1 = Sb[nh * 256 + nw];
        float sc = Sb[p];
        float v0 = fminf(fmaxf(sc - off0, lo), hi);
        float v1 = fminf(fmaxf(sc - off1, lo), hi);
        int i0 = 0, j0 = 0;
        bool ilo = false, jlo = false;
        #pragma unroll
        for (int k = 1; k < 8; ++k) {
            i0 += (v0 >= lev0[k]); ilo |= (v0 == lev0[k]);
            j0 += (v1 >= lev1[k]); jlo |= (v1 == lev1[k]);
        }
        float prod = v0 * v1;
        atomicAdd(&lh[(i0 * 8 + j0) * 64 + col], prod);
        if (ilo)        atomicAdd(&lh[((i0 - 1) * 8 + j0) * 64 + col], prod);
        if (jlo)        atomicAdd(&lh[(i0 * 8 + (j0 - 1)) * 64 + col], prod);
        if (ilo && jlo) atomicAdd(&lh[((i0 - 1) * 8 + (j0 - 1)) * 64 + col], prod);
    }
    __syncthreads();
    if (threadIdx.x < 64) {
        int bin = threadIdx.x;
        float s = 0.f;
        for (int c = 0; c < 64; ++c) s += lh[bin * 64 + ((c + bin) & 63)];
        ws[OFF_PH + blockIdx.x * 64 + bin] = s;
    }
}

// K4: per batch b — hist reduce, global total, expand+leaky, weighted instance-norm,
//     channel mix, and fold of the final 3x3 conv weights into per-cell tap dots:
//     D[b][tap][q][o] = sum_c leaky(bc[c] + sum_g wc[c][g]*yn[g][q][o]) * wf[c][tap]
__global__ void __launch_bounds__(256) k_fuse(const float* __restrict__ we,
                                              const float* __restrict__ be,
                                              const float* __restrict__ wc,
                                              const float* __restrict__ bc,
                                              const float* __restrict__ wf,
                                              float* ws)
{
    __shared__ float shY[4 * 3584];     // Y1 [g][q*56+o]
    __shared__ float sh_hist[256];      // [g][bin]
    __shared__ float sh_red[256];
    __shared__ float sh_wf[144];
    __shared__ float sh_we[168];
    __shared__ float sh_be[56];
    __shared__ float sh_wc[64];
    __shared__ float sh_bc[16];
    __shared__ float sh_stat[8];        // mean[4], istd[4]
    __shared__ float sw[4][8];
    __shared__ float sh_tot;
    int b = blockIdx.x;
    int tid = threadIdx.x;

    // phase A: per-bg hist bins
    {
        int g = tid >> 6, bin = tid & 63;
        float s = 0.f;
        #pragma unroll
        for (int c = 0; c < NCHH; ++c)
            s += ws[OFF_PH + ((b * 4 + g) * NCHH + c) * 64 + bin];
        sh_hist[tid] = s;
    }
    // phase B: global total over ALL partials (same sum as over all hist bins)
    {
        float s = 0.f;
        for (int k = 0; k < 256; ++k)
            s += ws[OFF_PH + k * 256 + tid];
        sh_red[tid] = s;
    }
    if (tid < 144) sh_wf[tid] = wf[tid];
    if (tid < 168) sh_we[tid] = we[tid];
    if (tid < 56)  sh_be[tid] = be[tid];
    if (tid < 64)  sh_wc[tid] = wc[tid];
    if (tid < 16)  sh_bc[tid] = bc[tid];
    __syncthreads();
    for (int k = 128; k > 0; k >>= 1) {
        if (tid < k) sh_red[tid] += sh_red[tid + k];
        __syncthreads();
    }
    if (tid == 0) sh_tot = sh_red[0];
    __syncthreads();
    float total = sh_tot;

    // phase C: Y1 + weighted stats (row repeat = 4 exactly; col repeat cnt(o))
    float ls[4] = {0.f, 0.f, 0.f, 0.f}, lss[4] = {0.f, 0.f, 0.f, 0.f};
    for (int it = 0; it < 56; ++it) {
        int g = it / 14;
        int rem = (it % 14) * 256 + tid;   // 0..3583 = q*56+o
        int q = rem / 56, o = rem % 56;
        float hv = sh_hist[g * 64 + q] / total;
        float y = sh_we[o * 3 + 0] * (float)(q >> 3)
                + sh_we[o * 3 + 1] * (float)(q & 7)
                + sh_we[o * 3 + 2] * hv + sh_be[o];
        y = leakyf(y);
        shY[g * 3584 + rem] = y;
        int cnt = ((32 * (o + 1) + 6) / 7) - ((32 * o + 6) / 7);
        float wgt = (float)(4 * cnt);
        ls[g]  += y * wgt;
        lss[g] += y * y * wgt;
    }
    #pragma unroll
    for (int g = 0; g < 4; ++g) {
        #pragma unroll
        for (int m = 1; m < 64; m <<= 1) {
            ls[g]  += __shfl_xor(ls[g], m);
            lss[g] += __shfl_xor(lss[g], m);
        }
    }
    int wid = tid >> 6, lane = tid & 63;
    if (lane == 0) {
        #pragma unroll
        for (int g = 0; g < 4; ++g) { sw[wid][g] = ls[g]; sw[wid][4 + g] = lss[g]; }
    }
    __syncthreads();
    if (tid < 4) {
        float m  = (sw[0][tid] + sw[1][tid] + sw[2][tid] + sw[3][tid]) / 65536.f;
        float sq = (sw[0][4 + tid] + sw[1][4 + tid] + sw[2][4 + tid] + sw[3][4 + tid]) / 65536.f;
        sh_stat[tid] = m;
        sh_stat[4 + tid] = 1.f / sqrtf(sq - m * m + 1e-5f);
    }
    __syncthreads();

    // phase D: channel mix + conv-weight fold -> D[b][t][q][o]
    for (int it = 0; it < 14; ++it) {
        int rem = it * 256 + tid;          // q*56+o
        float yn[4];
        #pragma unroll
        for (int g = 0; g < 4; ++g)
            yn[g] = (shY[g * 3584 + rem] - sh_stat[g]) * sh_stat[4 + g];
        float d[9] = {0.f, 0.f, 0.f, 0.f, 0.f, 0.f, 0.f, 0.f, 0.f};
        #pragma unroll
        for (int c = 0; c < 16; ++c) {
            float z = sh_bc[c];
            #pragma unroll
            for (int g = 0; g < 4; ++g) z += sh_wc[c * 4 + g] * yn[g];
            z = leakyf(z);
            #pragma unroll
            for (int t = 0; t < 9; ++t) d[t] += z * sh_wf[c * 9 + t];
        }
        #pragma unroll
        for (int t = 0; t < 9; ++t)
            ws[OFF_D + (b * 9 + t) * 3584 + rem] = d[t];
    }
}

// K5: out(h,w) = leaky(bf + sum_taps D[b][t][(h+kh-1)>>2][((w+kw-1)*7)>>5])
__global__ void __launch_bounds__(256) k_final(const float* __restrict__ ws,
                                               const float* __restrict__ bf,
                                               float* __restrict__ out)
{
    int pix = blockIdx.x * 256 + threadIdx.x;
    int w = pix & 255, h = (pix >> 8) & 255, b = pix >> 16;
    const float* Db = ws + OFF_D + b * 9 * 3584;
    float acc = 0.f;
    #pragma unroll
    for (int kh = 0; kh < 3; ++kh) {
        int h2 = h + kh - 1;
        if ((unsigned)h2 > 255u) continue;
        int qr = h2 >> 2;
        #pragma unroll
        for (int kw = 0; kw < 3; ++kw) {
            int w2 = w + kw - 1;
            if ((unsigned)w2 > 255u) continue;
            int oc = (w2 * 7) >> 5;
            acc += Db[(kh * 3 + kw) * 3584 + qr * 56 + oc];
        }
    }
    out[pix] = leakyf(acc + bf[0]);
}

extern "C" void kernel_launch(void* const* d_in, const int* in_sizes, int n_in,
                              void* d_out, int out_size, void* d_ws, size_t ws_size,
                              hipStream_t stream)
{
    const float* x   = (const float*)d_in[0];
    const float* we  = (const float*)d_in[1];
    const float* be  = (const float*)d_in[2];
    const float* wc  = (const float*)d_in[3];
    const float* bc  = (const float*)d_in[4];
    const float* wf  = (const float*)d_in[5];
    const float* bfi = (const float*)d_in[6];
    const float* clo = (const float*)d_in[7];
    const float* chi = (const float*)d_in[8];
    float* out = (float*)d_out;
    float* ws  = (float*)d_ws;

    dim3 blk(16, 16);
    dim3 grd(16, 16, NB);
    k_box<<<grd, blk, 0, stream>>>(x, ws);
    k_minmax_part<<<NB * NCHM, 256, 0, stream>>>(clo, chi, ws);
    k_hist_part<<<64 * NCHH, 256, 0, stream>>>(clo, chi, ws);
    k_fuse<<<NB, 256, 0, stream>>>(we, be, wc, bc, wf, ws);
    k_final<<<4096, 256, 0, stream>>>(ws, bfi, out);
}

// Round 4
// 153.221 us; speedup vs baseline: 1.0432x; 1.0432x over previous
//
#include <hip/hip_runtime.h>
#include <math.h>

// Problem constants
#define NB   16
#define HW   65536          // 256*256
#define NCHH 16             // hist pixel-chunks per (b,pair)

// Workspace layout (float offsets)
#define OFF_S    0          // [16][65536] channel-summed 3x3 box / 9 (dead after k_hist_part)
#define OFF_D    0          // [16][9][64][56] per-cell tap dot-products (overwrites dead S)
#define OFF_PH   1048576    // [1024][64] partial hists
#define OFF_PMN  1114112    // [128][64] partial mins (per 32x32 tile)
#define OFF_PMX  1122304    // [128][64] partial maxs
// total floats: 1130496 (~4.52 MB)

__device__ __forceinline__ float leakyf(float v) { return v >= 0.f ? v : 0.01f * v; }

// K1: fused 3x3 box filter (zero-padded, /9) + per-tile min/max partials for all
//     8 LBP directions. One block per 32x32 tile. S written for k_hist_part.
__global__ void __launch_bounds__(256) k_boxmm(const float* __restrict__ x,
                                               const float* __restrict__ clo,
                                               const float* __restrict__ chi,
                                               float* __restrict__ ws)
{
    __shared__ float inp[36][37];   // 3-channel-summed input, region [-2,+33]^2
    __shared__ float S[34][36];     // box output, region [-1,+32]^2
    const int doy[8] = {-1, 1, -1, 1, -1, 1, 0, 0};
    const int dox[8] = {-1, 1,  0, 0,  1, -1, 1, -1};
    int b = blockIdx.z;
    int h0 = blockIdx.y * 32, w0 = blockIdx.x * 32;
    int tid = threadIdx.x;
    const float* xb = x + (size_t)b * 3 * HW;
    for (int i = tid; i < 36 * 36; i += 256) {
        int lh = i / 36, lw = i % 36;
        int gh = h0 - 2 + lh, gw = w0 - 2 + lw;
        float v = 0.f;
        if ((unsigned)gh < 256u && (unsigned)gw < 256u) {
            int p = gh * 256 + gw;
            v = xb[p] + xb[HW + p] + xb[2 * HW + p];
        }
        inp[lh][lw] = v;
    }
    __syncthreads();
    for (int i = tid; i < 34 * 34; i += 256) {
        int lh = i / 34, lw = i % 34;
        float s = 0.f;
        #pragma unroll
        for (int dy = 0; dy < 3; ++dy)
            #pragma unroll
            for (int dx = 0; dx < 3; ++dx)
                s += inp[lh + dy][lw + dx];
        S[lh][lw] = s / 9.0f;
    }
    __syncthreads();
    // write center 32x32 of S (coalesced)
    #pragma unroll
    for (int i = 0; i < 4; ++i) {
        int idx = i * 256 + tid;
        int r = idx >> 5, c = idx & 31;
        ws[OFF_S + b * HW + (h0 + r) * 256 + (w0 + c)] = S[r + 1][c + 1];
    }
    // min/max of clipped diffs over the tile, all 8 directions
    float lo = clo[0], hi = chi[0];
    float vmn[8], vmx[8];
    #pragma unroll
    for (int o = 0; o < 8; ++o) { vmn[o] = 3.4e38f; vmx[o] = -3.4e38f; }
    #pragma unroll
    for (int i = 0; i < 4; ++i) {
        int idx = i * 256 + tid;
        int r = idx >> 5, c = idx & 31;
        int gh = h0 + r, gw = w0 + c;
        float sc = S[r + 1][c + 1];
        #pragma unroll
        for (int o = 0; o < 8; ++o) {
            int nh = gh + doy[o], nw = gw + dox[o];
            float off = ((unsigned)nh < 256u && (unsigned)nw < 256u)
                        ? S[r + 1 + doy[o]][c + 1 + dox[o]] : 0.f;
            float v = fminf(fmaxf(sc - off, lo), hi);
            vmn[o] = fminf(vmn[o], v);
            vmx[o] = fmaxf(vmx[o], v);
        }
    }
    #pragma unroll
    for (int o = 0; o < 8; ++o) {
        #pragma unroll
        for (int m = 1; m < 64; m <<= 1) {
            vmn[o] = fminf(vmn[o], __shfl_xor(vmn[o], m));
            vmx[o] = fmaxf(vmx[o], __shfl_xor(vmx[o], m));
        }
    }
    __shared__ float smn[4][8], smx[4][8];
    int wid = tid >> 6, lane = tid & 63;
    if (lane == 0) {
        #pragma unroll
        for (int o = 0; o < 8; ++o) { smn[wid][o] = vmn[o]; smx[wid][o] = vmx[o]; }
    }
    __syncthreads();
    if (tid < 8) {
        int o = tid;
        int tile = blockIdx.y * 8 + blockIdx.x;
        float mn = fminf(fminf(smn[0][o], smn[1][o]), fminf(smn[2][o], smn[3][o]));
        float mx = fmaxf(fmaxf(smx[0][o], smx[1][o]), fmaxf(smx[2][o], smx[3][o]));
        ws[OFF_PMN + (b * 8 + o) * 64 + tile] = mn;
        ws[OFF_PMX + (b * 8 + o) * 64 + tile] = mx;
    }
}

// K2: partial joint 8x8 histogram per (b, pair g, chunk). Parallel min/max reduce.
__global__ void __launch_bounds__(256) k_hist_part(const float* __restrict__ clo,
                                                   const float* __restrict__ chi,
                                                   float* ws)
{
    __shared__ float lh[64 * 64];   // [bin][col]
    __shared__ float sred[4];
    const int doy[8] = {-1, 1, -1, 1, -1, 1, 0, 0};
    const int dox[8] = {-1, 1,  0, 0,  1, -1, 1, -1};
    int bg = blockIdx.x / NCHH;
    int ch = blockIdx.x % NCHH;
    int b = bg >> 2, g = bg & 3;
    int dy0 = doy[2 * g], dx0 = dox[2 * g];
    int dy1 = doy[2 * g + 1], dx1 = dox[2 * g + 1];
    int tid = threadIdx.x;
    int warp = tid >> 6, lane = tid & 63;
    // parallel reduce of the 64 tile-partials: warp w handles one of mn0/mx0/mn1/mx1
    {
        int c0 = (b * 8 + 2 * g) * 64, c1 = (b * 8 + 2 * g + 1) * 64;
        float v;
        if      (warp == 0) v = ws[OFF_PMN + c0 + lane];
        else if (warp == 1) v = ws[OFF_PMX + c0 + lane];
        else if (warp == 2) v = ws[OFF_PMN + c1 + lane];
        else                v = ws[OFF_PMX + c1 + lane];
        bool isMin = (warp & 1) == 0;
        #pragma unroll
        for (int m = 1; m < 64; m <<= 1) {
            float o = __shfl_xor(v, m);
            v = isMin ? fminf(v, o) : fmaxf(v, o);
        }
        if (lane == 0) sred[warp] = v;
    }
    for (int i = tid; i < 4096; i += 256) lh[i] = 0.f;
    __syncthreads();
    float mn0 = sred[0], mx0 = sred[1], mn1 = sred[2], mx1 = sred[3];
    float r0 = mx0 - mn0, r1 = mx1 - mn1;
    float lev0[8], lev1[8];
    #pragma unroll
    for (int q = 0; q < 8; ++q) {
        lev0[q] = __fadd_rn(mn0, __fmul_rn(r0, (float)q * 0.125f));
        lev1[q] = __fadd_rn(mn1, __fmul_rn(r1, (float)q * 0.125f));
    }
    const float* Sb = ws + OFF_S + b * HW;
    int col = tid & 63;
    float lo = clo[0], hi = chi[0];
    int base = ch * (HW / NCHH);
    #pragma unroll
    for (int it = 0; it < (HW / NCHH) / 256; ++it) {
        int p = base + it * 256 + tid;
        int h = p >> 8, w = p & 255;
        float off0 = 0.f, off1 = 0.f;
        int nh = h + dy0, nw = w + dx0;
        if ((unsigned)nh < 256u && (unsigned)nw < 256u) off0 = Sb[nh * 256 + nw];
        nh = h + dy1; nw = w + dx1;
        if ((unsigned)nh < 256u && (unsigned)nw < 256u) off1 = Sb[nh * 256 + nw];
        float sc = Sb[p];
        float v0 = fminf(fmaxf(sc - off0, lo), hi);
        float v1 = fminf(fmaxf(sc - off1, lo), hi);
        int i0 = 0, j0 = 0;
        bool ilo = false, jlo = false;
        #pragma unroll
        for (int k = 1; k < 8; ++k) {
            i0 += (v0 >= lev0[k]); ilo |= (v0 == lev0[k]);
            j0 += (v1 >= lev1[k]); jlo |= (v1 == lev1[k]);
        }
        float prod = v0 * v1;
        atomicAdd(&lh[(i0 * 8 + j0) * 64 + col], prod);
        if (ilo)        atomicAdd(&lh[((i0 - 1) * 8 + j0) * 64 + col], prod);
        if (jlo)        atomicAdd(&lh[(i0 * 8 + (j0 - 1)) * 64 + col], prod);
        if (ilo && jlo) atomicAdd(&lh[((i0 - 1) * 8 + (j0 - 1)) * 64 + col], prod);
    }
    __syncthreads();
    if (tid < 64) {
        int bin = tid;
        float s = 0.f;
        for (int c = 0; c < 64; ++c) s += lh[bin * 64 + ((c + bin) & 63)];
        ws[OFF_PH + blockIdx.x * 64 + bin] = s;
    }
}

// K3: per batch b — hist reduce, global total, expand+leaky, weighted instance-norm,
//     channel mix, and fold of the final 3x3 conv weights into per-cell tap dots:
//     D[b][tap][q][o] = sum_c leaky(bc[c] + sum_g wc[c][g]*yn[g][q][o]) * wf[c][tap]
__global__ void __launch_bounds__(256) k_fuse(const float* __restrict__ we,
                                              const float* __restrict__ be,
                                              const float* __restrict__ wc,
                                              const float* __restrict__ bc,
                                              const float* __restrict__ wf,
                                              float* ws)
{
    __shared__ float shY[4 * 3584];     // Y1 [g][q*56+o]
    __shared__ float sh_hist[256];      // [g][bin]
    __shared__ float sh_red[256];
    __shared__ float sh_wf[144];
    __shared__ float sh_we[168];
    __shared__ float sh_be[56];
    __shared__ float sh_wc[64];
    __shared__ float sh_bc[16];
    __shared__ float sh_stat[8];        // mean[4], istd[4]
    __shared__ float sw[4][8];
    __shared__ float sh_tot;
    int b = blockIdx.x;
    int tid = threadIdx.x;

    // phase A: per-bg hist bins
    {
        int g = tid >> 6, bin = tid & 63;
        float s = 0.f;
        #pragma unroll
        for (int c = 0; c < NCHH; ++c)
            s += ws[OFF_PH + ((b * 4 + g) * NCHH + c) * 64 + bin];
        sh_hist[tid] = s;
    }
    // phase B: global total over ALL partials (same sum as over all hist bins)
    {
        const float4* ph4 = (const float4*)(ws + OFF_PH);
        float s = 0.f;
        for (int k = 0; k < 64; ++k) {
            float4 v = ph4[k * 256 + tid];
            s += v.x + v.y + v.z + v.w;
        }
        sh_red[tid] = s;
    }
    if (tid < 144) sh_wf[tid] = wf[tid];
    if (tid < 168) sh_we[tid] = we[tid];
    if (tid < 56)  sh_be[tid] = be[tid];
    if (tid < 64)  sh_wc[tid] = wc[tid];
    if (tid < 16)  sh_bc[tid] = bc[tid];
    __syncthreads();
    for (int k = 128; k > 0; k >>= 1) {
        if (tid < k) sh_red[tid] += sh_red[tid + k];
        __syncthreads();
    }
    if (tid == 0) sh_tot = sh_red[0];
    __syncthreads();
    float total = sh_tot;

    // phase C: Y1 + weighted stats (row repeat = 4 exactly; col repeat cnt(o))
    float ls[4] = {0.f, 0.f, 0.f, 0.f}, lss[4] = {0.f, 0.f, 0.f, 0.f};
    for (int it = 0; it < 56; ++it) {
        int g = it / 14;
        int rem = (it % 14) * 256 + tid;   // 0..3583 = q*56+o
        int q = rem / 56, o = rem % 56;
        float hv = sh_hist[g * 64 + q] / total;
        float y = sh_we[o * 3 + 0] * (float)(q >> 3)
                + sh_we[o * 3 + 1] * (float)(q & 7)
                + sh_we[o * 3 + 2] * hv + sh_be[o];
        y = leakyf(y);
        shY[g * 3584 + rem] = y;
        int cnt = ((32 * (o + 1) + 6) / 7) - ((32 * o + 6) / 7);
        float wgt = (float)(4 * cnt);
        ls[g]  += y * wgt;
        lss[g] += y * y * wgt;
    }
    #pragma unroll
    for (int g = 0; g < 4; ++g) {
        #pragma unroll
        for (int m = 1; m < 64; m <<= 1) {
            ls[g]  += __shfl_xor(ls[g], m);
            lss[g] += __shfl_xor(lss[g], m);
        }
    }
    int wid = tid >> 6, lane = tid & 63;
    if (lane == 0) {
        #pragma unroll
        for (int g = 0; g < 4; ++g) { sw[wid][g] = ls[g]; sw[wid][4 + g] = lss[g]; }
    }
    __syncthreads();
    if (tid < 4) {
        float m  = (sw[0][tid] + sw[1][tid] + sw[2][tid] + sw[3][tid]) / 65536.f;
        float sq = (sw[0][4 + tid] + sw[1][4 + tid] + sw[2][4 + tid] + sw[3][4 + tid]) / 65536.f;
        sh_stat[tid] = m;
        sh_stat[4 + tid] = 1.f / sqrtf(sq - m * m + 1e-5f);
    }
    __syncthreads();

    // phase D: channel mix + conv-weight fold -> D[b][t][q][o]
    for (int it = 0; it < 14; ++it) {
        int rem = it * 256 + tid;          // q*56+o
        float yn[4];
        #pragma unroll
        for (int g = 0; g < 4; ++g)
            yn[g] = (shY[g * 3584 + rem] - sh_stat[g]) * sh_stat[4 + g];
        float d[9] = {0.f, 0.f, 0.f, 0.f, 0.f, 0.f, 0.f, 0.f, 0.f};
        #pragma unroll
        for (int c = 0; c < 16; ++c) {
            float z = sh_bc[c];
            #pragma unroll
            for (int g = 0; g < 4; ++g) z += sh_wc[c * 4 + g] * yn[g];
            z = leakyf(z);
            #pragma unroll
            for (int t = 0; t < 9; ++t) d[t] += z * sh_wf[c * 9 + t];
        }
        #pragma unroll
        for (int t = 0; t < 9; ++t)
            ws[OFF_D + (b * 9 + t) * 3584 + rem] = d[t];
    }
}

// K4: out(h,w) = leaky(bf + sum_taps D[b][t][(h+kh-1)>>2][((w+kw-1)*7)>>5])
__global__ void __launch_bounds__(256) k_final(const float* __restrict__ ws,
                                               const float* __restrict__ bf,
                                               float* __restrict__ out)
{
    int pix = blockIdx.x * 256 + threadIdx.x;
    int w = pix & 255, h = (pix >> 8) & 255, b = pix >> 16;
    const float* Db = ws + OFF_D + b * 9 * 3584;
    float acc = 0.f;
    #pragma unroll
    for (int kh = 0; kh < 3; ++kh) {
        int h2 = h + kh - 1;
        if ((unsigned)h2 > 255u) continue;
        int qr = h2 >> 2;
        #pragma unroll
        for (int kw = 0; kw < 3; ++kw) {
            int w2 = w + kw - 1;
            if ((unsigned)w2 > 255u) continue;
            int oc = (w2 * 7) >> 5;
            acc += Db[(kh * 3 + kw) * 3584 + qr * 56 + oc];
        }
    }
    out[pix] = leakyf(acc + bf[0]);
}

extern "C" void kernel_launch(void* const* d_in, const int* in_sizes, int n_in,
                              void* d_out, int out_size, void* d_ws, size_t ws_size,
                              hipStream_t stream)
{
    const float* x   = (const float*)d_in[0];
    const float* we  = (const float*)d_in[1];
    const float* be  = (const float*)d_in[2];
    const float* wc  = (const float*)d_in[3];
    const float* bc  = (const float*)d_in[4];
    const float* wf  = (const float*)d_in[5];
    const float* bfi = (const float*)d_in[6];
    const float* clo = (const float*)d_in[7];
    const float* chi = (const float*)d_in[8];
    float* out = (float*)d_out;
    float* ws  = (float*)d_ws;

    k_boxmm<<<dim3(8, 8, NB), 256, 0, stream>>>(x, clo, chi, ws);
    k_hist_part<<<64 * NCHH, 256, 0, stream>>>(clo, chi, ws);
    k_fuse<<<NB, 256, 0, stream>>>(we, be, wc, bc, wf, ws);
    k_final<<<4096, 256, 0, stream>>>(ws, bfi, out);
}

// Round 5
// 131.468 us; speedup vs baseline: 1.2158x; 1.1655x over previous
//
#include <hip/hip_runtime.h>
#include <math.h>

// Problem constants
#define NB   16
#define HW   65536          // 256*256
#define NCHH 16             // hist pixel-chunks per (b,pair)

// Workspace layout (float offsets)
#define OFF_S    0          // [16][65536] channel-summed 3x3 box / 9 (dead after k_hist_part)
#define OFF_D    0          // [16][9][64][56] per-cell tap dot-products (overwrites dead S)
#define OFF_PH   1048576    // [1024][64] partial hists
#define OFF_PMN  1114112    // [128][64] partial mins (per 32x32 tile)
#define OFF_PMX  1122304    // [128][64] partial maxs
#define OFF_PT   1130496    // [1024] per-hist-block totals
// total floats: 1131520 (~4.53 MB)

__device__ __forceinline__ float leakyf(float v) { return v >= 0.f ? v : 0.01f * v; }

// K1: fused 3x3 box filter (zero-padded, /9) + per-tile min/max partials for all
//     8 LBP directions. One block per 32x32 tile. S written for k_hist_part.
__global__ void __launch_bounds__(256) k_boxmm(const float* __restrict__ x,
                                               const float* __restrict__ clo,
                                               const float* __restrict__ chi,
                                               float* __restrict__ ws)
{
    __shared__ float inp[36][37];   // 3-channel-summed input, region [-2,+33]^2
    __shared__ float S[34][36];     // box output, region [-1,+32]^2
    const int doy[8] = {-1, 1, -1, 1, -1, 1, 0, 0};
    const int dox[8] = {-1, 1,  0, 0,  1, -1, 1, -1};
    int b = blockIdx.z;
    int h0 = blockIdx.y * 32, w0 = blockIdx.x * 32;
    int tid = threadIdx.x;
    const float* xb = x + (size_t)b * 3 * HW;
    for (int i = tid; i < 36 * 36; i += 256) {
        int lh = i / 36, lw = i % 36;
        int gh = h0 - 2 + lh, gw = w0 - 2 + lw;
        float v = 0.f;
        if ((unsigned)gh < 256u && (unsigned)gw < 256u) {
            int p = gh * 256 + gw;
            v = xb[p] + xb[HW + p] + xb[2 * HW + p];
        }
        inp[lh][lw] = v;
    }
    __syncthreads();
    for (int i = tid; i < 34 * 34; i += 256) {
        int lh = i / 34, lw = i % 34;
        float s = 0.f;
        #pragma unroll
        for (int dy = 0; dy < 3; ++dy)
            #pragma unroll
            for (int dx = 0; dx < 3; ++dx)
                s += inp[lh + dy][lw + dx];
        S[lh][lw] = s / 9.0f;
    }
    __syncthreads();
    // write center 32x32 of S (coalesced)
    #pragma unroll
    for (int i = 0; i < 4; ++i) {
        int idx = i * 256 + tid;
        int r = idx >> 5, c = idx & 31;
        ws[OFF_S + b * HW + (h0 + r) * 256 + (w0 + c)] = S[r + 1][c + 1];
    }
    // min/max of clipped diffs over the tile, all 8 directions
    float lo = clo[0], hi = chi[0];
    float vmn[8], vmx[8];
    #pragma unroll
    for (int o = 0; o < 8; ++o) { vmn[o] = 3.4e38f; vmx[o] = -3.4e38f; }
    #pragma unroll
    for (int i = 0; i < 4; ++i) {
        int idx = i * 256 + tid;
        int r = idx >> 5, c = idx & 31;
        int gh = h0 + r, gw = w0 + c;
        float sc = S[r + 1][c + 1];
        #pragma unroll
        for (int o = 0; o < 8; ++o) {
            int nh = gh + doy[o], nw = gw + dox[o];
            float off = ((unsigned)nh < 256u && (unsigned)nw < 256u)
                        ? S[r + 1 + doy[o]][c + 1 + dox[o]] : 0.f;
            float v = fminf(fmaxf(sc - off, lo), hi);
            vmn[o] = fminf(vmn[o], v);
            vmx[o] = fmaxf(vmx[o], v);
        }
    }
    #pragma unroll
    for (int o = 0; o < 8; ++o) {
        #pragma unroll
        for (int m = 1; m < 64; m <<= 1) {
            vmn[o] = fminf(vmn[o], __shfl_xor(vmn[o], m));
            vmx[o] = fmaxf(vmx[o], __shfl_xor(vmx[o], m));
        }
    }
    __shared__ float smn[4][8], smx[4][8];
    int wid = tid >> 6, lane = tid & 63;
    if (lane == 0) {
        #pragma unroll
        for (int o = 0; o < 8; ++o) { smn[wid][o] = vmn[o]; smx[wid][o] = vmx[o]; }
    }
    __syncthreads();
    if (tid < 8) {
        int o = tid;
        int tile = blockIdx.y * 8 + blockIdx.x;
        float mn = fminf(fminf(smn[0][o], smn[1][o]), fminf(smn[2][o], smn[3][o]));
        float mx = fmaxf(fmaxf(smx[0][o], smx[1][o]), fmaxf(smx[2][o], smx[3][o]));
        ws[OFF_PMN + (b * 8 + o) * 64 + tile] = mn;
        ws[OFF_PMX + (b * 8 + o) * 64 + tile] = mx;
    }
}

// K2: partial joint 8x8 histogram per (b, pair g, chunk). Parallel min/max reduce.
//     Also writes per-block total PT for the global normalizer.
__global__ void __launch_bounds__(256) k_hist_part(const float* __restrict__ clo,
                                                   const float* __restrict__ chi,
                                                   float* ws)
{
    __shared__ float lh[64 * 64];   // [bin][col]
    __shared__ float sred[4];
    const int doy[8] = {-1, 1, -1, 1, -1, 1, 0, 0};
    const int dox[8] = {-1, 1,  0, 0,  1, -1, 1, -1};
    int bg = blockIdx.x / NCHH;
    int ch = blockIdx.x % NCHH;
    int b = bg >> 2, g = bg & 3;
    int dy0 = doy[2 * g], dx0 = dox[2 * g];
    int dy1 = doy[2 * g + 1], dx1 = dox[2 * g + 1];
    int tid = threadIdx.x;
    int warp = tid >> 6, lane = tid & 63;
    // parallel reduce of the 64 tile-partials: warp w handles one of mn0/mx0/mn1/mx1
    {
        int c0 = (b * 8 + 2 * g) * 64, c1 = (b * 8 + 2 * g + 1) * 64;
        float v;
        if      (warp == 0) v = ws[OFF_PMN + c0 + lane];
        else if (warp == 1) v = ws[OFF_PMX + c0 + lane];
        else if (warp == 2) v = ws[OFF_PMN + c1 + lane];
        else                v = ws[OFF_PMX + c1 + lane];
        bool isMin = (warp & 1) == 0;
        #pragma unroll
        for (int m = 1; m < 64; m <<= 1) {
            float o = __shfl_xor(v, m);
            v = isMin ? fminf(v, o) : fmaxf(v, o);
        }
        if (lane == 0) sred[warp] = v;
    }
    for (int i = tid; i < 4096; i += 256) lh[i] = 0.f;
    __syncthreads();
    float mn0 = sred[0], mx0 = sred[1], mn1 = sred[2], mx1 = sred[3];
    float r0 = mx0 - mn0, r1 = mx1 - mn1;
    float lev0[8], lev1[8];
    #pragma unroll
    for (int q = 0; q < 8; ++q) {
        lev0[q] = __fadd_rn(mn0, __fmul_rn(r0, (float)q * 0.125f));
        lev1[q] = __fadd_rn(mn1, __fmul_rn(r1, (float)q * 0.125f));
    }
    const float* Sb = ws + OFF_S + b * HW;
    int col = tid & 63;
    float lo = clo[0], hi = chi[0];
    int base = ch * (HW / NCHH);
    #pragma unroll
    for (int it = 0; it < (HW / NCHH) / 256; ++it) {
        int p = base + it * 256 + tid;
        int h = p >> 8, w = p & 255;
        float off0 = 0.f, off1 = 0.f;
        int nh = h + dy0, nw = w + dx0;
        if ((unsigned)nh < 256u && (unsigned)nw < 256u) off0 = Sb[nh * 256 + nw];
        nh = h + dy1; nw = w + dx1;
        if ((unsigned)nh < 256u && (unsigned)nw < 256u) off1 = Sb[nh * 256 + nw];
        float sc = Sb[p];
        float v0 = fminf(fmaxf(sc - off0, lo), hi);
        float v1 = fminf(fmaxf(sc - off1, lo), hi);
        int i0 = 0, j0 = 0;
        bool ilo = false, jlo = false;
        #pragma unroll
        for (int k = 1; k < 8; ++k) {
            i0 += (v0 >= lev0[k]); ilo |= (v0 == lev0[k]);
            j0 += (v1 >= lev1[k]); jlo |= (v1 == lev1[k]);
        }
        float prod = v0 * v1;
        atomicAdd(&lh[(i0 * 8 + j0) * 64 + col], prod);
        if (ilo)        atomicAdd(&lh[((i0 - 1) * 8 + j0) * 64 + col], prod);
        if (jlo)        atomicAdd(&lh[(i0 * 8 + (j0 - 1)) * 64 + col], prod);
        if (ilo && jlo) atomicAdd(&lh[((i0 - 1) * 8 + (j0 - 1)) * 64 + col], prod);
    }
    __syncthreads();
    if (tid < 64) {
        int bin = tid;
        float s = 0.f;
        for (int c = 0; c < 64; ++c) s += lh[bin * 64 + ((c + bin) & 63)];
        ws[OFF_PH + blockIdx.x * 64 + bin] = s;
        // block total (64 threads are one wave -> butterfly)
        float t = s;
        #pragma unroll
        for (int m = 1; m < 64; m <<= 1) t += __shfl_xor(t, m);
        if (bin == 0) ws[OFF_PT + blockIdx.x] = t;
    }
}

// K3: 112 blocks = 16 batches x 7 slices. Phases A-C redundant per batch slice
//     (cheap), phase D sliced: D[b][tap][q][o] = sum_c leaky(bc[c] +
//     sum_g wc[c][g]*yn[g][q][o]) * wf[c][tap]
__global__ void __launch_bounds__(256) k_fuse(const float* __restrict__ we,
                                              const float* __restrict__ be,
                                              const float* __restrict__ wc,
                                              const float* __restrict__ bc,
                                              const float* __restrict__ wf,
                                              float* ws)
{
    __shared__ float sh_hist[256];      // [g][bin]
    __shared__ float sh_red[256];
    __shared__ float sh_wf[144];
    __shared__ float sh_we[168];
    __shared__ float sh_be[56];
    __shared__ float sh_wc[64];
    __shared__ float sh_bc[16];
    __shared__ float sh_stat[8];        // mean[4], istd[4]
    __shared__ float sw[4][8];
    __shared__ float sh_tot;
    int b     = blockIdx.x / 7;
    int slice = blockIdx.x % 7;
    int tid = threadIdx.x;

    // phase A: per-(g,bin) hist sums for this batch
    {
        int g = tid >> 6, bin = tid & 63;
        float s = 0.f;
        #pragma unroll
        for (int c = 0; c < NCHH; ++c)
            s += ws[OFF_PH + ((b * 4 + g) * NCHH + c) * 64 + bin];
        sh_hist[tid] = s;
    }
    // phase B: global total via per-block totals (1024 floats)
    {
        float s = ws[OFF_PT + tid] + ws[OFF_PT + 256 + tid]
                + ws[OFF_PT + 512 + tid] + ws[OFF_PT + 768 + tid];
        sh_red[tid] = s;
    }
    if (tid < 144) sh_wf[tid] = wf[tid];
    if (tid < 168) sh_we[tid] = we[tid];
    if (tid < 56)  sh_be[tid] = be[tid];
    if (tid < 64)  sh_wc[tid] = wc[tid];
    if (tid < 16)  sh_bc[tid] = bc[tid];
    __syncthreads();
    for (int k = 128; k > 0; k >>= 1) {
        if (tid < k) sh_red[tid] += sh_red[tid + k];
        __syncthreads();
    }
    if (tid == 0) sh_tot = sh_red[0];
    __syncthreads();
    float total = sh_tot;

    // phase C: weighted instance-norm stats (row repeat = 4; col repeat cnt(o))
    float ls[4] = {0.f, 0.f, 0.f, 0.f}, lss[4] = {0.f, 0.f, 0.f, 0.f};
    for (int it = 0; it < 14; ++it) {
        int rem = it * 256 + tid;          // q*56+o
        int q = rem / 56, o = rem % 56;
        float base = sh_we[o * 3 + 0] * (float)(q >> 3)
                   + sh_we[o * 3 + 1] * (float)(q & 7) + sh_be[o];
        float w2 = sh_we[o * 3 + 2];
        int cnt = ((32 * (o + 1) + 6) / 7) - ((32 * o + 6) / 7);
        float wgt = (float)(4 * cnt);
        #pragma unroll
        for (int g = 0; g < 4; ++g) {
            float y = leakyf(base + w2 * (sh_hist[g * 64 + q] / total));
            ls[g]  += y * wgt;
            lss[g] += y * y * wgt;
        }
    }
    #pragma unroll
    for (int g = 0; g < 4; ++g) {
        #pragma unroll
        for (int m = 1; m < 64; m <<= 1) {
            ls[g]  += __shfl_xor(ls[g], m);
            lss[g] += __shfl_xor(lss[g], m);
        }
    }
    int wid = tid >> 6, lane = tid & 63;
    if (lane == 0) {
        #pragma unroll
        for (int g = 0; g < 4; ++g) { sw[wid][g] = ls[g]; sw[wid][4 + g] = lss[g]; }
    }
    __syncthreads();
    if (tid < 4) {
        float m  = (sw[0][tid] + sw[1][tid] + sw[2][tid] + sw[3][tid]) / 65536.f;
        float sq = (sw[0][4 + tid] + sw[1][4 + tid] + sw[2][4 + tid] + sw[3][4 + tid]) / 65536.f;
        sh_stat[tid] = m;
        sh_stat[4 + tid] = 1.f / sqrtf(sq - m * m + 1e-5f);
    }
    __syncthreads();

    // phase D: this slice's 2 iterations -> D[b][t][q][o]
    for (int it = slice * 2; it < slice * 2 + 2; ++it) {
        int rem = it * 256 + tid;          // q*56+o
        int q = rem / 56, o = rem % 56;
        float base = sh_we[o * 3 + 0] * (float)(q >> 3)
                   + sh_we[o * 3 + 1] * (float)(q & 7) + sh_be[o];
        float w2 = sh_we[o * 3 + 2];
        float yn[4];
        #pragma unroll
        for (int g = 0; g < 4; ++g) {
            float y = leakyf(base + w2 * (sh_hist[g * 64 + q] / total));
            yn[g] = (y - sh_stat[g]) * sh_stat[4 + g];
        }
        float d[9] = {0.f, 0.f, 0.f, 0.f, 0.f, 0.f, 0.f, 0.f, 0.f};
        #pragma unroll
        for (int c = 0; c < 16; ++c) {
            float z = sh_bc[c];
            #pragma unroll
            for (int g = 0; g < 4; ++g) z += sh_wc[c * 4 + g] * yn[g];
            z = leakyf(z);
            #pragma unroll
            for (int t = 0; t < 9; ++t) d[t] += z * sh_wf[c * 9 + t];
        }
        #pragma unroll
        for (int t = 0; t < 9; ++t)
            ws[OFF_D + (b * 9 + t) * 3584 + rem] = d[t];
    }
}

// K4: 4 pixels/thread, float4 store. out = leaky(bf + sum_taps D[...]).
__global__ void __launch_bounds__(256) k_final(const float* __restrict__ ws,
                                               const float* __restrict__ bf,
                                               float* __restrict__ out)
{
    int t4 = blockIdx.x * 256 + threadIdx.x;   // 0..262143 quad index
    int b = t4 >> 14;
    int rem = t4 & 16383;                      // h*64 + w0/4
    int h = rem >> 6, w0 = (rem & 63) * 4;
    const float* Db = ws + OFF_D + b * 9 * 3584;
    float bias = bf[0];
    float acc[4] = {bias, bias, bias, bias};
    #pragma unroll
    for (int kh = 0; kh < 3; ++kh) {
        int h2 = h + kh - 1;
        if ((unsigned)h2 > 255u) continue;
        int qr = h2 >> 2;
        #pragma unroll
        for (int kw = 0; kw < 3; ++kw) {
            const float* Dt = Db + (kh * 3 + kw) * 3584 + qr * 56;
            #pragma unroll
            for (int j = 0; j < 4; ++j) {
                int w2 = w0 + j + kw - 1;
                if ((unsigned)w2 <= 255u) acc[j] += Dt[(w2 * 7) >> 5];
            }
        }
    }
    float4 o4;
    o4.x = leakyf(acc[0]); o4.y = leakyf(acc[1]);
    o4.z = leakyf(acc[2]); o4.w = leakyf(acc[3]);
    ((float4*)out)[t4] = o4;
}

extern "C" void kernel_launch(void* const* d_in, const int* in_sizes, int n_in,
                              void* d_out, int out_size, void* d_ws, size_t ws_size,
                              hipStream_t stream)
{
    const float* x   = (const float*)d_in[0];
    const float* we  = (const float*)d_in[1];
    const float* be  = (const float*)d_in[2];
    const float* wc  = (const float*)d_in[3];
    const float* bc  = (const float*)d_in[4];
    const float* wf  = (const float*)d_in[5];
    const float* bfi = (const float*)d_in[6];
    const float* clo = (const float*)d_in[7];
    const float* chi = (const float*)d_in[8];
    float* out = (float*)d_out;
    float* ws  = (float*)d_ws;

    k_boxmm<<<dim3(8, 8, NB), 256, 0, stream>>>(x, clo, chi, ws);
    k_hist_part<<<64 * NCHH, 256, 0, stream>>>(clo, chi, ws);
    k_fuse<<<NB * 7, 256, 0, stream>>>(we, be, wc, bc, wf, ws);
    k_final<<<1024, 256, 0, stream>>>(ws, bfi, out);
}